// Round 6
// baseline (148.559 us; speedup 1.0000x reference)
//
#include <hip/hip_runtime.h>

// B=8, N=2048, D=32, H=4, HD=8, BH=32
// ws layout:
//   q16  [32][2048][8]  f16  (1MB)
//   k16  [32][2048][8]  f16  (1MB)
//   vT16 [32][16][2048] f16  (2MB)  rows 0..7 = V^T, row 8 = ones, 9..15 = 0
//   attn_ws [8][2048][32] f32 (2MB)
//
// R6: deep software pipeline. Groups of 4 j-tiles, depth-2 ping-pong register
// buffers: all loads of group g+1 issued before computing group g. c1 folded
// into f16 Q. Dual PV accumulators break the MFMA dependence chain.

typedef _Float16 f16;
typedef _Float16 f16x2 __attribute__((ext_vector_type(2)));
typedef _Float16 f16x4 __attribute__((ext_vector_type(4)));
typedef __fp16 h16x2 __attribute__((ext_vector_type(2)));
typedef float f32x4 __attribute__((ext_vector_type(4)));

__global__ __launch_bounds__(256) void qkv_kernel(
    const float* __restrict__ x, const float* __restrict__ Wqkv,
    const float* __restrict__ bqkv, f16* __restrict__ q16,
    f16* __restrict__ k16, f16* __restrict__ vT16) {
  __shared__ float Ws[32 * 96];
  __shared__ float bsh[96];
  __shared__ float xs[16 * 32];
  int tid = threadIdx.x;
  for (int i = tid; i < 32 * 96; i += 256) Ws[i] = Wqkv[i];
  if (tid < 96) bsh[tid] = bqkv[tid];
  int rowbase = blockIdx.x * 16;
  for (int i = tid; i < 16 * 32; i += 256) xs[i] = x[rowbase * 32 + i];
  __syncthreads();
#pragma unroll
  for (int e = 0; e < 6; ++e) {
    int idx = tid + e * 256;
    int r = idx / 96, c = idx % 96;
    float acc = bsh[c];
#pragma unroll
    for (int k = 0; k < 32; ++k) acc += xs[r * 32 + k] * Ws[k * 96 + c];
    int nrow = rowbase + r;
    int b = nrow >> 11, n = nrow & 2047;
    int s = c >> 5, h = (c >> 3) & 3, d = c & 7;
    int bh = b * 4 + h;
    if (s == 0)      q16[((size_t)bh * 2048 + n) * 8 + d] = (f16)acc;
    else if (s == 1) k16[((size_t)bh * 2048 + n) * 8 + d] = (f16)acc;
    else             vT16[((size_t)bh * 16 + d) * 2048 + n] = (f16)acc;
  }
  // fill vT16 rows 8..15 every launch (row 8 = ones for the denom trick)
  int f = (blockIdx.x * 256 + tid) * 2;
  int bh = f >> 14, rem = f & 16383;
  int row = rem >> 11, j = rem & 2047;
  f16 one = (f16)((row == 0) ? 1.f : 0.f);
  f16x2 val = {one, one};
  *(f16x2*)(vT16 + ((size_t)bh * 16 + 8 + row) * 2048 + j) = val;
}

// Issue all 12 loads of a 4-tile group (fully unrolled, static indices).
#define LOADG(S, G)                                               \
  {                                                               \
    const int t0_ = (G) * 4;                                      \
    _Pragma("unroll") for (int u = 0; u < 4; ++u) {               \
      k##S[u] = *(const f16x4*)(kp + (t0_ + u) * 128);            \
      v##S[u] = *(const f16x4*)(vp + (t0_ + u) * 16);             \
      a##S[u] = *(const f32x4*)(ap + (t0_ + u) * 16);             \
    }                                                             \
  }

// Compute a 4-tile group: QK mfma -> blend+exp2 -> pack -> PV mfma.
#define COMPG(S)                                                  \
  {                                                               \
    _Pragma("unroll") for (int u = 0; u < 4; ++u) {               \
      f32x4 s = __builtin_amdgcn_mfma_f32_16x16x16f16(            \
          k##S[u], qf, zero4, 0, 0, 0);                           \
      float e0 = __builtin_amdgcn_exp2f(fmaf(c2, a##S[u][0], s[0])); \
      float e1 = __builtin_amdgcn_exp2f(fmaf(c2, a##S[u][1], s[1])); \
      float e2 = __builtin_amdgcn_exp2f(fmaf(c2, a##S[u][2], s[2])); \
      float e3 = __builtin_amdgcn_exp2f(fmaf(c2, a##S[u][3], s[3])); \
      h16x2 h01 = __builtin_amdgcn_cvt_pkrtz(e0, e1);             \
      h16x2 h23 = __builtin_amdgcn_cvt_pkrtz(e2, e3);             \
      f16x4 pa;                                                   \
      pa[0] = (f16)(float)h01[0];                                 \
      pa[1] = (f16)(float)h01[1];                                 \
      pa[2] = (f16)(float)h23[0];                                 \
      pa[3] = (f16)(float)h23[1];                                 \
      if (u & 1)                                                  \
        acc1 = __builtin_amdgcn_mfma_f32_16x16x16f16(             \
            pa, v##S[u], acc1, 0, 0, 0);                          \
      else                                                        \
        acc0 = __builtin_amdgcn_mfma_f32_16x16x16f16(             \
            pa, v##S[u], acc0, 0, 0, 0);                          \
    }                                                             \
  }

__global__ __launch_bounds__(256) void attn_kernel(
    const f16* __restrict__ q16, const f16* __restrict__ k16,
    const f16* __restrict__ vT16, const float* __restrict__ adj,
    const float* __restrict__ gw_p, float* __restrict__ attn_ws) {
  int blk = blockIdx.x;
  int bh = blk & 31, qg = blk >> 5;     // bh fastest: 32 blocks share adj rows
  int wave = threadIdx.x >> 6, lane = threadIdx.x & 63;
  int b = bh >> 2, h = bh & 3;
  int qt0 = qg * 64 + wave * 16;
  int lq = lane & 15, lh = lane >> 4;

  const float LOG2E = 1.4426950408889634f;
  float gw = gw_p[0];
  float blend = 1.f / (1.f + __expf(-gw));
  float c1 = (1.f - blend) * 0.35355339059327373f * LOG2E;
  float c2 = blend * 5.f * LOG2E;

  const f16* qb = q16 + (size_t)bh * 2048 * 8;
  const f16* kp = k16 + (size_t)bh * 2048 * 8 + lq * 8 + lh * 4;
  const f16* vp = vT16 + (size_t)bh * 16 * 2048 + lq * 2048 + lh * 4;
  const float* ap = adj + (size_t)(qt0 + lq) * 2048 + lh * 4;

  // B operand (Q), with c1 pre-folded (saves a mul per score element).
  f16x4 qf = {};
  if (lane < 32) {
    f16x4 qraw = *(const f16x4*)(qb + (qt0 + lq) * 8 + lh * 4);
    qf[0] = (f16)(c1 * (float)qraw[0]);
    qf[1] = (f16)(c1 * (float)qraw[1]);
    qf[2] = (f16)(c1 * (float)qraw[2]);
    qf[3] = (f16)(c1 * (float)qraw[3]);
  }

  f32x4 acc0 = {0.f, 0.f, 0.f, 0.f};
  f32x4 acc1 = {0.f, 0.f, 0.f, 0.f};
  const f32x4 zero4 = {0.f, 0.f, 0.f, 0.f};

  f16x4 kA[4], vA[4], kB[4], vB[4];
  f32x4 aA[4], aB[4];

  // 32 groups of 4 tiles; depth-2 ping-pong: group g+1's loads are in
  // flight while group g computes.
  LOADG(A, 0);
  for (int g = 0; g < 32; g += 2) {
    LOADG(B, g + 1);
    COMPG(A);
    if (g + 2 < 32) { LOADG(A, g + 2); }
    COMPG(B);
  }
  f32x4 acc;
  acc[0] = acc0[0] + acc1[0];
  acc[1] = acc0[1] + acc1[1];
  acc[2] = acc0[2] + acc1[2];
  acc[3] = acc0[3] + acc1[3];

  // acc(l,r) = out[q=lh*4+r][d=lq]; denominator lives at lane (lh*16)|8
  int dsrc = (lane & 48) | 8;
  float den0 = __shfl(acc[0], dsrc);
  float den1 = __shfl(acc[1], dsrc);
  float den2 = __shfl(acc[2], dsrc);
  float den3 = __shfl(acc[3], dsrc);
  if (lq < 8) {
    size_t base = ((size_t)b * 2048 + qt0 + lh * 4) * 32 + h * 8 + lq;
    attn_ws[base]      = acc[0] / den0;
    attn_ws[base + 32] = acc[1] / den1;
    attn_ws[base + 64] = acc[2] / den2;
    attn_ws[base + 96] = acc[3] / den3;
  }
}

__global__ __launch_bounds__(256) void out_ln_kernel(
    const float* __restrict__ attn_ws, const float* __restrict__ x,
    const float* __restrict__ Wout, const float* __restrict__ bout,
    const float* __restrict__ gamma, const float* __restrict__ beta,
    float* __restrict__ out) {
  __shared__ float Ws[32 * 32];
  __shared__ float bs[32], gs[32], bts[32];
  int tid = threadIdx.x;
  for (int i = tid; i < 1024; i += 256) Ws[i] = Wout[i];
  if (tid < 32) { bs[tid] = bout[tid]; gs[tid] = gamma[tid]; bts[tid] = beta[tid]; }
  __syncthreads();
  int row = blockIdx.x * 8 + (tid >> 5);
  int d = tid & 31;
  const float* ar = attn_ws + (size_t)row * 32;
  float acc = bs[d];
#pragma unroll
  for (int k = 0; k < 32; ++k) acc += ar[k] * Ws[k * 32 + d];
  float res = acc + x[(size_t)row * 32 + d];
  float s1 = res, s2 = res * res;
#pragma unroll
  for (int off = 16; off >= 1; off >>= 1) {
    s1 += __shfl_xor(s1, off);
    s2 += __shfl_xor(s2, off);
  }
  float mu = s1 * 0.03125f;
  float var = s2 * 0.03125f - mu * mu;
  float r = rsqrtf(var + 1e-5f);
  out[(size_t)row * 32 + d] = (res - mu) * r * gs[d] + bts[d];
}

extern "C" void kernel_launch(void* const* d_in, const int* in_sizes, int n_in,
                              void* d_out, int out_size, void* d_ws, size_t ws_size,
                              hipStream_t stream) {
  const float* x     = (const float*)d_in[0];
  const float* adj   = (const float*)d_in[1];
  const float* gw    = (const float*)d_in[2];
  const float* Wqkv  = (const float*)d_in[3];
  const float* bqkv  = (const float*)d_in[4];
  const float* Wout  = (const float*)d_in[5];
  const float* bout  = (const float*)d_in[6];
  const float* gamma = (const float*)d_in[7];
  const float* beta  = (const float*)d_in[8];
  float* out = (float*)d_out;

  char* wsb = (char*)d_ws;
  f16* q16      = (f16*)wsb;                    // 1MB
  f16* k16      = (f16*)(wsb + (1 << 20));      // 1MB
  f16* vT16     = (f16*)(wsb + (2 << 20));      // 2MB
  float* attn_ws = (float*)(wsb + (4 << 20));   // 2MB

  qkv_kernel<<<1024, 256, 0, stream>>>(x, Wqkv, bqkv, q16, k16, vT16);
  attn_kernel<<<1024, 256, 0, stream>>>(q16, k16, vT16, adj, gw, attn_ws);
  out_ln_kernel<<<2048, 256, 0, stream>>>(attn_ws, x, Wout, bout, gamma, beta, out);
}

// Round 7
// 148.260 us; speedup vs baseline: 1.0020x; 1.0020x over previous
//
#include <hip/hip_runtime.h>

// B=8, N=2048, D=32, H=4, HD=8, BH=32
// ws layout:
//   q16  [32][2048][8]  f16  (1MB)
//   k16  [32][2048][8]  f16  (1MB)
//   vT16 [32][16][2048] f16  (2MB)  rows 0..7 = V^T, row 8 = ones, 9..15 = 0
//   attn_ws [8][2048][32] f32 (2MB)
//
// R7: TLP latency hiding. 512-thread blocks = 8 waves: 4 q-tiles x 2 j-halves.
// Fixed-max softmax => j-split merge is a pure add through 4KB LDS.
// 1024 blocks x 8 waves = 32 waves/CU (100% occupancy at VGPR<=64).

typedef _Float16 f16;
typedef _Float16 f16x2 __attribute__((ext_vector_type(2)));
typedef _Float16 f16x4 __attribute__((ext_vector_type(4)));
typedef __fp16 h16x2 __attribute__((ext_vector_type(2)));
typedef float f32x4 __attribute__((ext_vector_type(4)));

__global__ __launch_bounds__(256) void qkv_kernel(
    const float* __restrict__ x, const float* __restrict__ Wqkv,
    const float* __restrict__ bqkv, f16* __restrict__ q16,
    f16* __restrict__ k16, f16* __restrict__ vT16) {
  __shared__ float Ws[32 * 96];
  __shared__ float bsh[96];
  __shared__ float xs[16 * 32];
  int tid = threadIdx.x;
  for (int i = tid; i < 32 * 96; i += 256) Ws[i] = Wqkv[i];
  if (tid < 96) bsh[tid] = bqkv[tid];
  int rowbase = blockIdx.x * 16;
  for (int i = tid; i < 16 * 32; i += 256) xs[i] = x[rowbase * 32 + i];
  __syncthreads();
#pragma unroll
  for (int e = 0; e < 6; ++e) {
    int idx = tid + e * 256;
    int r = idx / 96, c = idx % 96;
    float acc = bsh[c];
#pragma unroll
    for (int k = 0; k < 32; ++k) acc += xs[r * 32 + k] * Ws[k * 96 + c];
    int nrow = rowbase + r;
    int b = nrow >> 11, n = nrow & 2047;
    int s = c >> 5, h = (c >> 3) & 3, d = c & 7;
    int bh = b * 4 + h;
    if (s == 0)      q16[((size_t)bh * 2048 + n) * 8 + d] = (f16)acc;
    else if (s == 1) k16[((size_t)bh * 2048 + n) * 8 + d] = (f16)acc;
    else             vT16[((size_t)bh * 16 + d) * 2048 + n] = (f16)acc;
  }
  // fill vT16 rows 8..15 every launch (row 8 = ones for the denom trick)
  int f = (blockIdx.x * 256 + tid) * 2;
  int bh = f >> 14, rem = f & 16383;
  int row = rem >> 11, j = rem & 2047;
  f16 one = (f16)((row == 0) ? 1.f : 0.f);
  f16x2 val = {one, one};
  *(f16x2*)(vT16 + ((size_t)bh * 16 + 8 + row) * 2048 + j) = val;
}

__global__ __launch_bounds__(512, 8) void attn_kernel(
    const f16* __restrict__ q16, const f16* __restrict__ k16,
    const f16* __restrict__ vT16, const float* __restrict__ adj,
    const float* __restrict__ gw_p, float* __restrict__ attn_ws) {
  int blk = blockIdx.x;
  int bh = blk & 31, qg = blk >> 5;     // bh fastest: 32 blocks share adj rows
  int tid = threadIdx.x;
  int wave = tid >> 6, lane = tid & 63;
  int qtile = wave & 3, jhalf = wave >> 2;  // 4 q-tiles x 2 j-halves
  int b = bh >> 2, h = bh & 3;
  int qt0 = qg * 64 + qtile * 16;
  int lq = lane & 15, lh = lane >> 4;

  const float LOG2E = 1.4426950408889634f;
  float gw = gw_p[0];
  float blend = 1.f / (1.f + __expf(-gw));
  float c1 = (1.f - blend) * 0.35355339059327373f * LOG2E;
  float c2 = blend * 5.f * LOG2E;

  // per-wave base pointers; jhalf offsets by 64 j-tiles
  const f16* qb = q16 + (size_t)bh * 2048 * 8;
  const f16* kp = k16 + (size_t)bh * 2048 * 8 + jhalf * 64 * 128 + lq * 8 + lh * 4;
  const f16* vp = vT16 + (size_t)bh * 16 * 2048 + jhalf * 64 * 16 + lq * 2048 + lh * 4;
  const float* ap = adj + (size_t)(qt0 + lq) * 2048 + jhalf * 64 * 16 + lh * 4;

  // B operand (Q), c1 pre-folded. Lanes >=32 zero (K-rows 8..15 of QK mfma).
  f16x4 qf = {};
  if (lane < 32) {
    f16x4 qraw = *(const f16x4*)(qb + (qt0 + lq) * 8 + lh * 4);
    qf[0] = (f16)(c1 * (float)qraw[0]);
    qf[1] = (f16)(c1 * (float)qraw[1]);
    qf[2] = (f16)(c1 * (float)qraw[2]);
    qf[3] = (f16)(c1 * (float)qraw[3]);
  }

  f32x4 acc0 = {0.f, 0.f, 0.f, 0.f};
  f32x4 acc1 = {0.f, 0.f, 0.f, 0.f};
  const f32x4 zero4 = {0.f, 0.f, 0.f, 0.f};

  // 64 j-tiles per wave; unroll 4 for immediate address offsets.
  // K loads unmasked: lanes>=32 read garbage that lands in zero B-rows
  // (contributes 0); addresses stay inside the workspace (vT16 follows k16).
#pragma unroll 4
  for (int t = 0; t < 64; ++t) {
    f16x4 kf = *(const f16x4*)(kp + t * 128);
    f16x4 vf = *(const f16x4*)(vp + t * 16);
    f32x4 av = *(const f32x4*)(ap + t * 16);
    f32x4 s = __builtin_amdgcn_mfma_f32_16x16x16f16(kf, qf, zero4, 0, 0, 0);
    float e0 = __builtin_amdgcn_exp2f(fmaf(c2, av[0], s[0]));
    float e1 = __builtin_amdgcn_exp2f(fmaf(c2, av[1], s[1]));
    float e2 = __builtin_amdgcn_exp2f(fmaf(c2, av[2], s[2]));
    float e3 = __builtin_amdgcn_exp2f(fmaf(c2, av[3], s[3]));
    h16x2 h01 = __builtin_amdgcn_cvt_pkrtz(e0, e1);
    h16x2 h23 = __builtin_amdgcn_cvt_pkrtz(e2, e3);
    f16x4 pa;
    pa[0] = (f16)(float)h01[0];
    pa[1] = (f16)(float)h01[1];
    pa[2] = (f16)(float)h23[0];
    pa[3] = (f16)(float)h23[1];
    if (t & 1)
      acc1 = __builtin_amdgcn_mfma_f32_16x16x16f16(pa, vf, acc1, 0, 0, 0);
    else
      acc0 = __builtin_amdgcn_mfma_f32_16x16x16f16(pa, vf, acc0, 0, 0, 0);
  }
  f32x4 acc;
  acc[0] = acc0[0] + acc1[0];
  acc[1] = acc0[1] + acc1[1];
  acc[2] = acc0[2] + acc1[2];
  acc[3] = acc0[3] + acc1[3];

  // j-split merge: waves 4..7 dump partials to LDS; waves 0..3 add.
  __shared__ float lds[4 * 64 * 4];
  if (jhalf) *(f32x4*)&lds[(qtile * 64 + lane) * 4] = acc;
  __syncthreads();
  if (jhalf == 0) {
    f32x4 other = *(const f32x4*)&lds[(qtile * 64 + lane) * 4];
    acc[0] += other[0]; acc[1] += other[1];
    acc[2] += other[2]; acc[3] += other[3];

    // acc(l,r) = out[q=qt0+lh*4+r][d=lq]; denominator at lane (lh*16)|8
    int dsrc = (lane & 48) | 8;
    float den0 = __shfl(acc[0], dsrc);
    float den1 = __shfl(acc[1], dsrc);
    float den2 = __shfl(acc[2], dsrc);
    float den3 = __shfl(acc[3], dsrc);
    if (lq < 8) {
      size_t base = ((size_t)b * 2048 + qt0 + lh * 4) * 32 + h * 8 + lq;
      attn_ws[base]      = acc[0] / den0;
      attn_ws[base + 32] = acc[1] / den1;
      attn_ws[base + 64] = acc[2] / den2;
      attn_ws[base + 96] = acc[3] / den3;
    }
  }
}

__global__ __launch_bounds__(256) void out_ln_kernel(
    const float* __restrict__ attn_ws, const float* __restrict__ x,
    const float* __restrict__ Wout, const float* __restrict__ bout,
    const float* __restrict__ gamma, const float* __restrict__ beta,
    float* __restrict__ out) {
  __shared__ float Ws[32 * 32];
  __shared__ float bs[32], gs[32], bts[32];
  int tid = threadIdx.x;
  for (int i = tid; i < 1024; i += 256) Ws[i] = Wout[i];
  if (tid < 32) { bs[tid] = bout[tid]; gs[tid] = gamma[tid]; bts[tid] = beta[tid]; }
  __syncthreads();
  int row = blockIdx.x * 8 + (tid >> 5);
  int d = tid & 31;
  const float* ar = attn_ws + (size_t)row * 32;
  float acc = bs[d];
#pragma unroll
  for (int k = 0; k < 32; ++k) acc += ar[k] * Ws[k * 32 + d];
  float res = acc + x[(size_t)row * 32 + d];
  float s1 = res, s2 = res * res;
#pragma unroll
  for (int off = 16; off >= 1; off >>= 1) {
    s1 += __shfl_xor(s1, off);
    s2 += __shfl_xor(s2, off);
  }
  float mu = s1 * 0.03125f;
  float var = s2 * 0.03125f - mu * mu;
  float r = rsqrtf(var + 1e-5f);
  out[(size_t)row * 32 + d] = (res - mu) * r * gs[d] + bts[d];
}

extern "C" void kernel_launch(void* const* d_in, const int* in_sizes, int n_in,
                              void* d_out, int out_size, void* d_ws, size_t ws_size,
                              hipStream_t stream) {
  const float* x     = (const float*)d_in[0];
  const float* adj   = (const float*)d_in[1];
  const float* gw    = (const float*)d_in[2];
  const float* Wqkv  = (const float*)d_in[3];
  const float* bqkv  = (const float*)d_in[4];
  const float* Wout  = (const float*)d_in[5];
  const float* bout  = (const float*)d_in[6];
  const float* gamma = (const float*)d_in[7];
  const float* beta  = (const float*)d_in[8];
  float* out = (float*)d_out;

  char* wsb = (char*)d_ws;
  f16* q16      = (f16*)wsb;                    // 1MB
  f16* k16      = (f16*)(wsb + (1 << 20));      // 1MB
  f16* vT16     = (f16*)(wsb + (2 << 20));      // 2MB
  float* attn_ws = (float*)(wsb + (4 << 20));   // 2MB

  qkv_kernel<<<1024, 256, 0, stream>>>(x, Wqkv, bqkv, q16, k16, vT16);
  attn_kernel<<<1024, 512, 0, stream>>>(q16, k16, vT16, adj, gw, attn_ws);
  out_ln_kernel<<<2048, 256, 0, stream>>>(attn_ws, x, Wout, bout, gamma, beta, out);
}

// Round 8
// 79.985 us; speedup vs baseline: 1.8573x; 1.8536x over previous
//
#include <hip/hip_runtime.h>

// B=8, N=2048, D=32, H=4, HD=8, BH=32
// ws layout (full path, 23MB):
//   q16    [32][2048][8]        f16  (1MB)  @ 0
//   kf_ws  [32][128][64][4]     f16  (2MB)  @ 1MB   K in MFMA-A fragment order
//   vf_ws  [32][128][64][4]     f16  (2MB)  @ 3MB   V^T in MFMA-B fragment order
//   adj_sw [128][128][64][4]    f32  (16MB) @ 5MB   adj in C-fragment order
//   attn_ws[8][2048][32]        f32  (2MB)  @ 21MB
//
// R8: all hot loads in fragment order -> one dense 64-lane burst each
// (512B/512B/1KB per 16x16 tile) instead of 16-row strided gathers.

typedef _Float16 f16;
typedef _Float16 f16x2 __attribute__((ext_vector_type(2)));
typedef _Float16 f16x4 __attribute__((ext_vector_type(4)));
typedef __fp16 h16x2 __attribute__((ext_vector_type(2)));
typedef float f32x4 __attribute__((ext_vector_type(4)));

// Fill constant fragment lanes: kf lanes>=32 = 0; vf d-col 8 = 1, 9..15 = 0.
__global__ __launch_bounds__(256) void fill_kernel(f16* __restrict__ kf_ws,
                                                   f16* __restrict__ vf_ws) {
  int gid = blockIdx.x * 256 + threadIdx.x;  // 4096 tiles * 64 lanes
  int lane = gid & 63;
  const f16x4 z = {};
  if (lane >= 32) *(f16x4*)(kf_ws + (size_t)gid * 4) = z;
  int dq = lane & 15;
  if (dq == 8) {
    f16x4 ones = {(f16)1.f, (f16)1.f, (f16)1.f, (f16)1.f};
    *(f16x4*)(vf_ws + (size_t)gid * 4) = ones;
  } else if (dq > 8) {
    *(f16x4*)(vf_ws + (size_t)gid * 4) = z;
  }
}

// adj -> C-fragment order: adj_sw[qt][jt][lane][e] = adj[qt*16+(l&15)][jt*16+(l>>4)*4+e]
__global__ __launch_bounds__(256) void adjswz_kernel(const float* __restrict__ adj,
                                                     float* __restrict__ adj_sw) {
  int tile = blockIdx.x * 4 + (threadIdx.x >> 6);  // 16384 tiles (qt*128+jt)
  int lane = threadIdx.x & 63;
  int qt = tile >> 7, jt = tile & 127;
  f32x4 v = *(const f32x4*)(adj + (size_t)(qt * 16 + (lane & 15)) * 2048 +
                            jt * 16 + (lane >> 4) * 4);
  *(f32x4*)(adj_sw + ((size_t)tile * 64 + lane) * 4) = v;
}

__global__ __launch_bounds__(256) void qkv_kernel(
    const float* __restrict__ x, const float* __restrict__ Wqkv,
    const float* __restrict__ bqkv, f16* __restrict__ q16,
    f16* __restrict__ kf_ws, f16* __restrict__ vf_ws) {
  __shared__ float Ws[32 * 96];
  __shared__ float bsh[96];
  __shared__ float xs[16 * 32];
  int tid = threadIdx.x;
  for (int i = tid; i < 32 * 96; i += 256) Ws[i] = Wqkv[i];
  if (tid < 96) bsh[tid] = bqkv[tid];
  int rowbase = blockIdx.x * 16;
  for (int i = tid; i < 16 * 32; i += 256) xs[i] = x[rowbase * 32 + i];
  __syncthreads();
#pragma unroll
  for (int e = 0; e < 6; ++e) {
    int idx = tid + e * 256;
    int r = idx / 96, c = idx % 96;
    float acc = bsh[c];
#pragma unroll
    for (int k = 0; k < 32; ++k) acc += xs[r * 32 + k] * Ws[k * 96 + c];
    int nrow = rowbase + r;
    int b = nrow >> 11, n = nrow & 2047;
    int s = c >> 5, h = (c >> 3) & 3, d = c & 7;
    int bh = b * 4 + h;
    int jt = n >> 4, jr = n & 15;
    if (s == 0) {
      q16[((size_t)bh * 2048 + n) * 8 + d] = (f16)acc;
    } else if (s == 1) {
      // K fragment: lane = (d>>2)*16 + jr, elem = d&3
      int lane = ((d >> 2) << 4) | jr;
      kf_ws[(((size_t)bh * 128 + jt) * 64 + lane) * 4 + (d & 3)] = (f16)acc;
    } else {
      // V fragment: lane = (jr>>2)*16 + d, elem = jr&3
      int lane = ((jr >> 2) << 4) | d;
      vf_ws[(((size_t)bh * 128 + jt) * 64 + lane) * 4 + (jr & 3)] = (f16)acc;
    }
  }
}

template <bool SWZ>
__global__ __launch_bounds__(512, 8) void attn_kernel(
    const f16* __restrict__ q16, const f16* __restrict__ kf_ws,
    const f16* __restrict__ vf_ws, const float* __restrict__ adj_or_sw,
    const float* __restrict__ gw_p, float* __restrict__ attn_ws) {
  int blk = blockIdx.x;
  int bh = blk & 31, qg = blk >> 5;     // bh fastest: 32 blocks share adj
  int tid = threadIdx.x;
  int wave = tid >> 6, lane = tid & 63;
  int qtile = wave & 3, jhalf = wave >> 2;  // 4 q-tiles x 2 j-halves
  int b = bh >> 2, h = bh & 3;
  int qt = qg * 4 + qtile;              // global q-tile index 0..127
  int qt0 = qt * 16;
  int lq = lane & 15, lh = lane >> 4;

  const float LOG2E = 1.4426950408889634f;
  float gw = gw_p[0];
  float blend = 1.f / (1.f + __expf(-gw));
  float c1 = (1.f - blend) * 0.35355339059327373f * LOG2E;
  float c2 = blend * 5.f * LOG2E;

  // dense fragment streams; jhalf offsets by 64 tiles
  const f16* kp = kf_ws + (((size_t)bh * 128 + jhalf * 64) * 64 + lane) * 4;
  const f16* vp = vf_ws + (((size_t)bh * 128 + jhalf * 64) * 64 + lane) * 4;
  const float* ap;
  if (SWZ)
    ap = adj_or_sw + (((size_t)qt * 128 + jhalf * 64) * 64 + lane) * 4;
  else
    ap = adj_or_sw + (size_t)(qt0 + lq) * 2048 + jhalf * 1024 + lh * 4;

  f16x4 qf = {};
  if (lane < 32) {
    f16x4 qraw = *(const f16x4*)(q16 + ((size_t)bh * 2048 + qt0 + lq) * 8 + lh * 4);
    qf[0] = (f16)(c1 * (float)qraw[0]);
    qf[1] = (f16)(c1 * (float)qraw[1]);
    qf[2] = (f16)(c1 * (float)qraw[2]);
    qf[3] = (f16)(c1 * (float)qraw[3]);
  }

  f32x4 acc0 = {0.f, 0.f, 0.f, 0.f};
  f32x4 acc1 = {0.f, 0.f, 0.f, 0.f};
  const f32x4 zero4 = {0.f, 0.f, 0.f, 0.f};

#pragma unroll 4
  for (int t = 0; t < 64; ++t) {
    f16x4 kf = *(const f16x4*)(kp + t * 256);
    f16x4 vf = *(const f16x4*)(vp + t * 256);
    f32x4 av;
    if (SWZ) av = *(const f32x4*)(ap + t * 256);
    else     av = *(const f32x4*)(ap + t * 16);
    f32x4 s = __builtin_amdgcn_mfma_f32_16x16x16f16(kf, qf, zero4, 0, 0, 0);
    float e0 = __builtin_amdgcn_exp2f(fmaf(c2, av[0], s[0]));
    float e1 = __builtin_amdgcn_exp2f(fmaf(c2, av[1], s[1]));
    float e2 = __builtin_amdgcn_exp2f(fmaf(c2, av[2], s[2]));
    float e3 = __builtin_amdgcn_exp2f(fmaf(c2, av[3], s[3]));
    h16x2 h01 = __builtin_amdgcn_cvt_pkrtz(e0, e1);
    h16x2 h23 = __builtin_amdgcn_cvt_pkrtz(e2, e3);
    f16x4 pa;
    pa[0] = (f16)(float)h01[0];
    pa[1] = (f16)(float)h01[1];
    pa[2] = (f16)(float)h23[0];
    pa[3] = (f16)(float)h23[1];
    if (t & 1)
      acc1 = __builtin_amdgcn_mfma_f32_16x16x16f16(pa, vf, acc1, 0, 0, 0);
    else
      acc0 = __builtin_amdgcn_mfma_f32_16x16x16f16(pa, vf, acc0, 0, 0, 0);
  }
  f32x4 acc;
  acc[0] = acc0[0] + acc1[0];
  acc[1] = acc0[1] + acc1[1];
  acc[2] = acc0[2] + acc1[2];
  acc[3] = acc0[3] + acc1[3];

  // j-split merge: waves 4..7 dump partials to LDS; waves 0..3 add.
  __shared__ float lds[4 * 64 * 4];
  if (jhalf) *(f32x4*)&lds[(qtile * 64 + lane) * 4] = acc;
  __syncthreads();
  if (jhalf == 0) {
    f32x4 other = *(const f32x4*)&lds[(qtile * 64 + lane) * 4];
    acc[0] += other[0]; acc[1] += other[1];
    acc[2] += other[2]; acc[3] += other[3];

    // acc(l,r) = out[q=qt0+lh*4+r][d=lq]; denominator at lane (lh*16)|8
    int dsrc = (lane & 48) | 8;
    float den0 = __shfl(acc[0], dsrc);
    float den1 = __shfl(acc[1], dsrc);
    float den2 = __shfl(acc[2], dsrc);
    float den3 = __shfl(acc[3], dsrc);
    if (lq < 8) {
      size_t base = ((size_t)b * 2048 + qt0 + lh * 4) * 32 + h * 8 + lq;
      attn_ws[base]      = acc[0] / den0;
      attn_ws[base + 32] = acc[1] / den1;
      attn_ws[base + 64] = acc[2] / den2;
      attn_ws[base + 96] = acc[3] / den3;
    }
  }
}

__global__ __launch_bounds__(256) void out_ln_kernel(
    const float* __restrict__ attn_ws, const float* __restrict__ x,
    const float* __restrict__ Wout, const float* __restrict__ bout,
    const float* __restrict__ gamma, const float* __restrict__ beta,
    float* __restrict__ out) {
  __shared__ float Ws[32 * 32];
  __shared__ float bs[32], gs[32], bts[32];
  int tid = threadIdx.x;
  for (int i = tid; i < 1024; i += 256) Ws[i] = Wout[i];
  if (tid < 32) { bs[tid] = bout[tid]; gs[tid] = gamma[tid]; bts[tid] = beta[tid]; }
  __syncthreads();
  int row = blockIdx.x * 8 + (tid >> 5);
  int d = tid & 31;
  const float* ar = attn_ws + (size_t)row * 32;
  float acc = bs[d];
#pragma unroll
  for (int k = 0; k < 32; ++k) acc += ar[k] * Ws[k * 32 + d];
  float res = acc + x[(size_t)row * 32 + d];
  float s1 = res, s2 = res * res;
#pragma unroll
  for (int off = 16; off >= 1; off >>= 1) {
    s1 += __shfl_xor(s1, off);
    s2 += __shfl_xor(s2, off);
  }
  float mu = s1 * 0.03125f;
  float var = s2 * 0.03125f - mu * mu;
  float r = rsqrtf(var + 1e-5f);
  out[(size_t)row * 32 + d] = (res - mu) * r * gs[d] + bts[d];
}

extern "C" void kernel_launch(void* const* d_in, const int* in_sizes, int n_in,
                              void* d_out, int out_size, void* d_ws, size_t ws_size,
                              hipStream_t stream) {
  const float* x     = (const float*)d_in[0];
  const float* adj   = (const float*)d_in[1];
  const float* gw    = (const float*)d_in[2];
  const float* Wqkv  = (const float*)d_in[3];
  const float* bqkv  = (const float*)d_in[4];
  const float* Wout  = (const float*)d_in[5];
  const float* bout  = (const float*)d_in[6];
  const float* gamma = (const float*)d_in[7];
  const float* beta  = (const float*)d_in[8];
  float* out = (float*)d_out;

  char* wsb = (char*)d_ws;
  f16* q16       = (f16*)wsb;                         // 1MB
  f16* kf_ws     = (f16*)(wsb + (1 << 20));           // 2MB
  f16* vf_ws     = (f16*)(wsb + (3 << 20));           // 2MB
  float* adj_sw  = (float*)(wsb + (5 << 20));         // 16MB
  bool full = ws_size >= (size_t)(23 << 20);
  float* attn_ws = (float*)(wsb + (full ? (21 << 20) : (5 << 20)));  // 2MB

  fill_kernel<<<1024, 256, 0, stream>>>(kf_ws, vf_ws);
  qkv_kernel<<<1024, 256, 0, stream>>>(x, Wqkv, bqkv, q16, kf_ws, vf_ws);
  if (full) {
    adjswz_kernel<<<4096, 256, 0, stream>>>(adj, adj_sw);
    attn_kernel<true><<<1024, 512, 0, stream>>>(q16, kf_ws, vf_ws, adj_sw, gw, attn_ws);
  } else {
    attn_kernel<false><<<1024, 512, 0, stream>>>(q16, kf_ws, vf_ws, adj, gw, attn_ws);
  }
  out_ln_kernel<<<2048, 256, 0, stream>>>(attn_ws, x, Wout, bout, gamma, beta, out);
}

// Round 9
// 61.875 us; speedup vs baseline: 2.4010x; 1.2927x over previous
//
#include <hip/hip_runtime.h>

// B=8, N=2048, D=32, H=4, HD=8, BH=32
// ws layout (15MB):
//   q16    [32][2048][8]          f16 (1MB)  @ 0
//   kf_ws  [32][128][64][4]       f16 (2MB)  @ 1MB   K in MFMA-A fragment order
//   vf_ws  [32][128][64][4]       f16 (2MB)  @ 3MB   V^T in MFMA-B fragment order
//   adj16  [64][128][64][8]       f16 (8MB)  @ 5MB   c2*adj, C-frag order, qt-PAIR packed
//   attn_ws[8][2048][32]          f32 (2MB)  @ 13MB
//
// R9: L2-byte diet. f16 adj with c2 folded (halves biggest stream); 2 q-tiles
// per wave so each K/V fragment load feeds 2 mfma pairs; both qt adj rows in
// one dwordx4. 393MB total vs R8's 1.02GB.

typedef _Float16 f16;
typedef _Float16 f16x2 __attribute__((ext_vector_type(2)));
typedef _Float16 f16x4 __attribute__((ext_vector_type(4)));
typedef _Float16 f16x8 __attribute__((ext_vector_type(8)));
typedef __fp16 h16x2 __attribute__((ext_vector_type(2)));
typedef float f32x4 __attribute__((ext_vector_type(4)));

// Fill constant fragment lanes: kf lanes>=32 = 0; vf d-col 8 = 1, 9..15 = 0.
__global__ __launch_bounds__(256) void fill_kernel(f16* __restrict__ kf_ws,
                                                   f16* __restrict__ vf_ws) {
  int gid = blockIdx.x * 256 + threadIdx.x;  // 4096 tiles * 64 lanes
  int lane = gid & 63;
  const f16x4 z = {};
  if (lane >= 32) *(f16x4*)(kf_ws + (size_t)gid * 4) = z;
  int dq = lane & 15;
  if (dq == 8) {
    f16x4 ones = {(f16)1.f, (f16)1.f, (f16)1.f, (f16)1.f};
    *(f16x4*)(vf_ws + (size_t)gid * 4) = ones;
  } else if (dq > 8) {
    *(f16x4*)(vf_ws + (size_t)gid * 4) = z;
  }
}

// adj -> f16 C-fragment order with c2 folded, qt-pair packed:
// adj16[qtp][jt][lane][e] ; e<4 -> qt=2*qtp, e>=4 -> qt=2*qtp+1
//   value = c2 * adj[qt*16 + (lane&15)][jt*16 + (lane>>4)*4 + (e&3)]
__global__ __launch_bounds__(256) void adjswz_kernel(const float* __restrict__ adj,
                                                     const float* __restrict__ gw_p,
                                                     f16* __restrict__ adj16) {
  const float LOG2E = 1.4426950408889634f;
  float blend = 1.f / (1.f + __expf(-gw_p[0]));
  float c2 = blend * 5.f * LOG2E;
  int gid = blockIdx.x * 256 + threadIdx.x;   // 2048 blocks: 8192 tiles * 64
  int tile = gid >> 6, lane = gid & 63;
  int qtp = tile >> 7, jt = tile & 127;
  int col = jt * 16 + (lane >> 4) * 4;
  f32x4 v0 = *(const f32x4*)(adj + (size_t)(qtp * 32 + (lane & 15)) * 2048 + col);
  f32x4 v1 = *(const f32x4*)(adj + (size_t)(qtp * 32 + 16 + (lane & 15)) * 2048 + col);
  f16x8 r;
  r[0] = (f16)(c2 * v0[0]); r[1] = (f16)(c2 * v0[1]);
  r[2] = (f16)(c2 * v0[2]); r[3] = (f16)(c2 * v0[3]);
  r[4] = (f16)(c2 * v1[0]); r[5] = (f16)(c2 * v1[1]);
  r[6] = (f16)(c2 * v1[2]); r[7] = (f16)(c2 * v1[3]);
  *(f16x8*)(adj16 + (size_t)gid * 8) = r;
}

__global__ __launch_bounds__(256) void qkv_kernel(
    const float* __restrict__ x, const float* __restrict__ Wqkv,
    const float* __restrict__ bqkv, f16* __restrict__ q16,
    f16* __restrict__ kf_ws, f16* __restrict__ vf_ws) {
  __shared__ float Ws[32 * 96];
  __shared__ float bsh[96];
  __shared__ float xs[16 * 32];
  int tid = threadIdx.x;
  for (int i = tid; i < 32 * 96; i += 256) Ws[i] = Wqkv[i];
  if (tid < 96) bsh[tid] = bqkv[tid];
  int rowbase = blockIdx.x * 16;
  for (int i = tid; i < 16 * 32; i += 256) xs[i] = x[rowbase * 32 + i];
  __syncthreads();
#pragma unroll
  for (int e = 0; e < 6; ++e) {
    int idx = tid + e * 256;
    int r = idx / 96, c = idx % 96;
    float acc = bsh[c];
#pragma unroll
    for (int k = 0; k < 32; ++k) acc += xs[r * 32 + k] * Ws[k * 96 + c];
    int nrow = rowbase + r;
    int b = nrow >> 11, n = nrow & 2047;
    int s = c >> 5, h = (c >> 3) & 3, d = c & 7;
    int bh = b * 4 + h;
    int jt = n >> 4, jr = n & 15;
    if (s == 0) {
      q16[((size_t)bh * 2048 + n) * 8 + d] = (f16)acc;
    } else if (s == 1) {
      int lane = ((d >> 2) << 4) | jr;   // K frag: lane=(d>>2)*16+jr, e=d&3
      kf_ws[(((size_t)bh * 128 + jt) * 64 + lane) * 4 + (d & 3)] = (f16)acc;
    } else {
      int lane = ((jr >> 2) << 4) | d;   // V frag: lane=(jr>>2)*16+d, e=jr&3
      vf_ws[(((size_t)bh * 128 + jt) * 64 + lane) * 4 + (jr & 3)] = (f16)acc;
    }
  }
}

__global__ __launch_bounds__(512, 8) void attn_kernel(
    const f16* __restrict__ q16, const f16* __restrict__ kf_ws,
    const f16* __restrict__ vf_ws, const f16* __restrict__ adj16,
    const float* __restrict__ gw_p, float* __restrict__ attn_ws) {
  int blk = blockIdx.x;
  int bh = blk & 31, qg = blk >> 5;     // bh fastest: 32 blocks share adj
  int tid = threadIdx.x;
  int wave = tid >> 6, lane = tid & 63;
  int qtp = wave & 1, jq = wave >> 1;   // 2 qt-pairs x 4 j-quarters
  int b = bh >> 2, h = bh & 3;
  int qt0g = qg * 4 + qtp * 2;          // first of this wave's two q-tiles
  int lq = lane & 15, lh = lane >> 4;

  const float LOG2E = 1.4426950408889634f;
  float blend = 1.f / (1.f + __expf(-gw_p[0]));
  float c1 = (1.f - blend) * 0.35355339059327373f * LOG2E;

  // streams; jq offsets by 32 tiles
  const f16* kp = kf_ws + (((size_t)bh * 128 + jq * 32) * 64 + lane) * 4;
  const f16* vp = vf_ws + (((size_t)bh * 128 + jq * 32) * 64 + lane) * 4;
  const f16* ap = adj16 + ((((size_t)(qg * 2 + qtp)) * 128 + jq * 32) * 64 + lane) * 8;

  f16x4 qf0 = {}, qf1 = {};
  if (lane < 32) {
    f16x4 qa = *(const f16x4*)(q16 + ((size_t)bh * 2048 + qt0g * 16 + lq) * 8 + lh * 4);
    f16x4 qb = *(const f16x4*)(q16 + ((size_t)bh * 2048 + (qt0g + 1) * 16 + lq) * 8 + lh * 4);
    qf0[0] = (f16)(c1 * (float)qa[0]); qf0[1] = (f16)(c1 * (float)qa[1]);
    qf0[2] = (f16)(c1 * (float)qa[2]); qf0[3] = (f16)(c1 * (float)qa[3]);
    qf1[0] = (f16)(c1 * (float)qb[0]); qf1[1] = (f16)(c1 * (float)qb[1]);
    qf1[2] = (f16)(c1 * (float)qb[2]); qf1[3] = (f16)(c1 * (float)qb[3]);
  }

  f32x4 acc0 = {0.f, 0.f, 0.f, 0.f};
  f32x4 acc1 = {0.f, 0.f, 0.f, 0.f};
  const f32x4 zero4 = {0.f, 0.f, 0.f, 0.f};

#pragma unroll 4
  for (int t = 0; t < 32; ++t) {
    f16x4 kf = *(const f16x4*)(kp + t * 256);
    f16x4 vf = *(const f16x4*)(vp + t * 256);
    f16x8 av = *(const f16x8*)(ap + t * 512);
    f32x4 s0 = __builtin_amdgcn_mfma_f32_16x16x16f16(kf, qf0, zero4, 0, 0, 0);
    f32x4 s1 = __builtin_amdgcn_mfma_f32_16x16x16f16(kf, qf1, zero4, 0, 0, 0);
    float e0 = __builtin_amdgcn_exp2f(s0[0] + (float)av[0]);
    float e1 = __builtin_amdgcn_exp2f(s0[1] + (float)av[1]);
    float e2 = __builtin_amdgcn_exp2f(s0[2] + (float)av[2]);
    float e3 = __builtin_amdgcn_exp2f(s0[3] + (float)av[3]);
    float f0 = __builtin_amdgcn_exp2f(s1[0] + (float)av[4]);
    float f1 = __builtin_amdgcn_exp2f(s1[1] + (float)av[5]);
    float f2 = __builtin_amdgcn_exp2f(s1[2] + (float)av[6]);
    float f3 = __builtin_amdgcn_exp2f(s1[3] + (float)av[7]);
    h16x2 p01 = __builtin_amdgcn_cvt_pkrtz(e0, e1);
    h16x2 p23 = __builtin_amdgcn_cvt_pkrtz(e2, e3);
    h16x2 q01 = __builtin_amdgcn_cvt_pkrtz(f0, f1);
    h16x2 q23 = __builtin_amdgcn_cvt_pkrtz(f2, f3);
    f16x4 pa0, pa1;
    pa0[0] = (f16)(float)p01[0]; pa0[1] = (f16)(float)p01[1];
    pa0[2] = (f16)(float)p23[0]; pa0[3] = (f16)(float)p23[1];
    pa1[0] = (f16)(float)q01[0]; pa1[1] = (f16)(float)q01[1];
    pa1[2] = (f16)(float)q23[0]; pa1[3] = (f16)(float)q23[1];
    acc0 = __builtin_amdgcn_mfma_f32_16x16x16f16(pa0, vf, acc0, 0, 0, 0);
    acc1 = __builtin_amdgcn_mfma_f32_16x16x16f16(pa1, vf, acc1, 0, 0, 0);
  }

  // merge 4 j-quarter partials: waves jq=1..3 dump, jq=0 adds.
  __shared__ float lds[2][3][64][8];
  if (jq) {
    *(f32x4*)&lds[qtp][jq - 1][lane][0] = acc0;
    *(f32x4*)&lds[qtp][jq - 1][lane][4] = acc1;
  }
  __syncthreads();
  if (jq == 0) {
#pragma unroll
    for (int p = 0; p < 3; ++p) {
      f32x4 o0 = *(const f32x4*)&lds[qtp][p][lane][0];
      f32x4 o1 = *(const f32x4*)&lds[qtp][p][lane][4];
      acc0[0] += o0[0]; acc0[1] += o0[1]; acc0[2] += o0[2]; acc0[3] += o0[3];
      acc1[0] += o1[0]; acc1[1] += o1[1]; acc1[2] += o1[2]; acc1[3] += o1[3];
    }
    // acc(l,r) = out[q = lh*4+r][d = lq]; denominator at lane (lh*16)|8
    int dsrc = (lane & 48) | 8;
    float d00 = __shfl(acc0[0], dsrc), d01 = __shfl(acc0[1], dsrc);
    float d02 = __shfl(acc0[2], dsrc), d03 = __shfl(acc0[3], dsrc);
    float d10 = __shfl(acc1[0], dsrc), d11 = __shfl(acc1[1], dsrc);
    float d12 = __shfl(acc1[2], dsrc), d13 = __shfl(acc1[3], dsrc);
    if (lq < 8) {
      size_t base0 = ((size_t)b * 2048 + qt0g * 16 + lh * 4) * 32 + h * 8 + lq;
      attn_ws[base0]      = acc0[0] / d00;
      attn_ws[base0 + 32] = acc0[1] / d01;
      attn_ws[base0 + 64] = acc0[2] / d02;
      attn_ws[base0 + 96] = acc0[3] / d03;
      size_t base1 = base0 + 16 * 32;
      attn_ws[base1]      = acc1[0] / d10;
      attn_ws[base1 + 32] = acc1[1] / d11;
      attn_ws[base1 + 64] = acc1[2] / d12;
      attn_ws[base1 + 96] = acc1[3] / d13;
    }
  }
}

__global__ __launch_bounds__(256) void out_ln_kernel(
    const float* __restrict__ attn_ws, const float* __restrict__ x,
    const float* __restrict__ Wout, const float* __restrict__ bout,
    const float* __restrict__ gamma, const float* __restrict__ beta,
    float* __restrict__ out) {
  __shared__ float Ws[32 * 32];
  __shared__ float bs[32], gs[32], bts[32];
  int tid = threadIdx.x;
  for (int i = tid; i < 1024; i += 256) Ws[i] = Wout[i];
  if (tid < 32) { bs[tid] = bout[tid]; gs[tid] = gamma[tid]; bts[tid] = beta[tid]; }
  __syncthreads();
  int row = blockIdx.x * 8 + (tid >> 5);
  int d = tid & 31;
  const float* ar = attn_ws + (size_t)row * 32;
  float acc = bs[d];
#pragma unroll
  for (int k = 0; k < 32; ++k) acc += ar[k] * Ws[k * 32 + d];
  float res = acc + x[(size_t)row * 32 + d];
  float s1 = res, s2 = res * res;
#pragma unroll
  for (int off = 16; off >= 1; off >>= 1) {
    s1 += __shfl_xor(s1, off);
    s2 += __shfl_xor(s2, off);
  }
  float mu = s1 * 0.03125f;
  float var = s2 * 0.03125f - mu * mu;
  float r = rsqrtf(var + 1e-5f);
  out[(size_t)row * 32 + d] = (res - mu) * r * gs[d] + bts[d];
}

extern "C" void kernel_launch(void* const* d_in, const int* in_sizes, int n_in,
                              void* d_out, int out_size, void* d_ws, size_t ws_size,
                              hipStream_t stream) {
  const float* x     = (const float*)d_in[0];
  const float* adj   = (const float*)d_in[1];
  const float* gw    = (const float*)d_in[2];
  const float* Wqkv  = (const float*)d_in[3];
  const float* bqkv  = (const float*)d_in[4];
  const float* Wout  = (const float*)d_in[5];
  const float* bout  = (const float*)d_in[6];
  const float* gamma = (const float*)d_in[7];
  const float* beta  = (const float*)d_in[8];
  float* out = (float*)d_out;

  char* wsb = (char*)d_ws;
  f16* q16       = (f16*)wsb;                     // 1MB
  f16* kf_ws     = (f16*)(wsb + (1 << 20));       // 2MB
  f16* vf_ws     = (f16*)(wsb + (3 << 20));       // 2MB
  f16* adj16     = (f16*)(wsb + (5 << 20));       // 8MB
  float* attn_ws = (float*)(wsb + (13 << 20));    // 2MB

  fill_kernel<<<1024, 256, 0, stream>>>(kf_ws, vf_ws);
  qkv_kernel<<<1024, 256, 0, stream>>>(x, Wqkv, bqkv, q16, kf_ws, vf_ws);
  adjswz_kernel<<<2048, 256, 0, stream>>>(adj, gw, adj16);
  attn_kernel<<<1024, 512, 0, stream>>>(q16, kf_ws, vf_ws, adj16, gw, attn_ws);
  out_ln_kernel<<<2048, 256, 0, stream>>>(attn_ws, x, Wout, bout, gamma, beta, out);
}

// Round 10
// 54.748 us; speedup vs baseline: 2.7135x; 1.1302x over previous
//
#include <hip/hip_runtime.h>

// B=8, N=2048, D=32, H=4, HD=8, BH=32
// ws layout (15MB):
//   q16    [32][2048][8]          f16 (1MB)  @ 0
//   kf_ws  [32][128][64][4]       f16 (2MB)  @ 1MB   K in MFMA-A fragment order
//   vf_ws  [32][128][64][4]       f16 (2MB)  @ 3MB   V^T in MFMA-B fragment order
//   adj16  [64][128][64][8]       f16 (8MB)  @ 5MB   c2*adj, C-frag order, qt-pair packed
//   attn_ws[8][2048][32]          f32 (2MB)  @ 13MB
//
// R10: register-batched (2 bh x 4 qt) per wave -> 512B of L2 traffic per
// 16x16 tile (R9: 1KB). adj multiplicity 32->16, K/V 64->32. 256MB total.
// 512 blocks = 32 qt-quads x 16 bh-pairs (bhp fastest: blocks sharing an
// adj slice are adjacent); 8 waves = 8 j-splits; 64KB-LDS parallel merge.

typedef _Float16 f16;
typedef _Float16 f16x2 __attribute__((ext_vector_type(2)));
typedef _Float16 f16x4 __attribute__((ext_vector_type(4)));
typedef _Float16 f16x8 __attribute__((ext_vector_type(8)));
typedef __fp16 h16x2 __attribute__((ext_vector_type(2)));
typedef float f32x4 __attribute__((ext_vector_type(4)));

// adj -> f16 C-fragment order with c2 folded, qt-pair packed; plus the
// constant fragment fill (kf lanes>=32 = 0; vf d-col 8 = ones, 9..15 = 0).
__global__ __launch_bounds__(256) void prep_kernel(const float* __restrict__ adj,
                                                   const float* __restrict__ gw_p,
                                                   f16* __restrict__ adj16,
                                                   f16* __restrict__ kf_ws,
                                                   f16* __restrict__ vf_ws) {
  const float LOG2E = 1.4426950408889634f;
  float blend = 1.f / (1.f + __expf(-gw_p[0]));
  float c2 = blend * 5.f * LOG2E;
  int gid = blockIdx.x * 256 + threadIdx.x;   // 2048 blocks: 8192 tiles * 64
  int tile = gid >> 6, lane = gid & 63;
  int qtp = tile >> 7, jt = tile & 127;
  int col = jt * 16 + (lane >> 4) * 4;
  f32x4 v0 = *(const f32x4*)(adj + (size_t)(qtp * 32 + (lane & 15)) * 2048 + col);
  f32x4 v1 = *(const f32x4*)(adj + (size_t)(qtp * 32 + 16 + (lane & 15)) * 2048 + col);
  f16x8 r;
  r[0] = (f16)(c2 * v0[0]); r[1] = (f16)(c2 * v0[1]);
  r[2] = (f16)(c2 * v0[2]); r[3] = (f16)(c2 * v0[3]);
  r[4] = (f16)(c2 * v1[0]); r[5] = (f16)(c2 * v1[1]);
  r[6] = (f16)(c2 * v1[2]); r[7] = (f16)(c2 * v1[3]);
  *(f16x8*)(adj16 + (size_t)gid * 8) = r;
  // fused fill: first 262144 threads cover 4096 k/v fragment tiles
  if (gid < 262144) {
    const f16x4 z = {};
    if (lane >= 32) *(f16x4*)(kf_ws + (size_t)gid * 4) = z;
    int dq = lane & 15;
    if (dq == 8) {
      f16x4 ones = {(f16)1.f, (f16)1.f, (f16)1.f, (f16)1.f};
      *(f16x4*)(vf_ws + (size_t)gid * 4) = ones;
    } else if (dq > 8) {
      *(f16x4*)(vf_ws + (size_t)gid * 4) = z;
    }
  }
}

__global__ __launch_bounds__(256) void qkv_kernel(
    const float* __restrict__ x, const float* __restrict__ Wqkv,
    const float* __restrict__ bqkv, f16* __restrict__ q16,
    f16* __restrict__ kf_ws, f16* __restrict__ vf_ws) {
  __shared__ float Ws[32 * 96];
  __shared__ float bsh[96];
  __shared__ float xs[16 * 32];
  int tid = threadIdx.x;
  for (int i = tid; i < 32 * 96; i += 256) Ws[i] = Wqkv[i];
  if (tid < 96) bsh[tid] = bqkv[tid];
  int rowbase = blockIdx.x * 16;
  for (int i = tid; i < 16 * 32; i += 256) xs[i] = x[rowbase * 32 + i];
  __syncthreads();
#pragma unroll
  for (int e = 0; e < 6; ++e) {
    int idx = tid + e * 256;
    int r = idx / 96, c = idx % 96;
    float acc = bsh[c];
#pragma unroll
    for (int k = 0; k < 32; ++k) acc += xs[r * 32 + k] * Ws[k * 96 + c];
    int nrow = rowbase + r;
    int b = nrow >> 11, n = nrow & 2047;
    int s = c >> 5, h = (c >> 3) & 3, d = c & 7;
    int bh = b * 4 + h;
    int jt = n >> 4, jr = n & 15;
    if (s == 0) {
      q16[((size_t)bh * 2048 + n) * 8 + d] = (f16)acc;
    } else if (s == 1) {
      int lane = ((d >> 2) << 4) | jr;   // K frag: lane=(d>>2)*16+jr, e=d&3
      kf_ws[(((size_t)bh * 128 + jt) * 64 + lane) * 4 + (d & 3)] = (f16)acc;
    } else {
      int lane = ((jr >> 2) << 4) | d;   // V frag: lane=(jr>>2)*16+d, e=jr&3
      vf_ws[(((size_t)bh * 128 + jt) * 64 + lane) * 4 + (jr & 3)] = (f16)acc;
    }
  }
}

__global__ __launch_bounds__(512, 4) void attn_kernel(
    const f16* __restrict__ q16, const f16* __restrict__ kf_ws,
    const f16* __restrict__ vf_ws, const f16* __restrict__ adj16,
    const float* __restrict__ gw_p, float* __restrict__ attn_ws) {
  int blk = blockIdx.x;
  int bhp = blk & 15, qtq = blk >> 4;   // bhp fastest: adj-sharing blocks adjacent
  int tid = threadIdx.x;
  int w = tid >> 6, lane = tid & 63;    // w = j-split (16 jt each)
  int lq = lane & 15, lh = lane >> 4;
  int bh0 = bhp * 2;

  const float LOG2E = 1.4426950408889634f;
  float blend = 1.f / (1.f + __expf(-gw_p[0]));
  float c1 = (1.f - blend) * 0.35355339059327373f * LOG2E;

  const f16* kp0 = kf_ws + (((size_t)bh0 * 128 + w * 16) * 64 + lane) * 4;
  const f16* kp1 = kp0 + (size_t)128 * 64 * 4;              // bh0+1
  const f16* vp0 = vf_ws + (((size_t)bh0 * 128 + w * 16) * 64 + lane) * 4;
  const f16* vp1 = vp0 + (size_t)128 * 64 * 4;
  const f16* ap0 = adj16 + (((size_t)(qtq * 2) * 128 + w * 16) * 64 + lane) * 8;
  const f16* ap1 = ap0 + (size_t)128 * 64 * 8;              // qtp+1

  // Q fragments, c1 pre-folded: qf[u][m] for bh=bh0+u, qt=qtq*4+m
  f16x4 qf[2][4];
#pragma unroll
  for (int u = 0; u < 2; ++u)
#pragma unroll
    for (int m = 0; m < 4; ++m) {
      f16x4 t = {};
      if (lane < 32) {
        f16x4 qr = *(const f16x4*)(q16 + ((size_t)(bh0 + u) * 2048 +
                                          (qtq * 4 + m) * 16 + lq) * 8 + lh * 4);
        t[0] = (f16)(c1 * (float)qr[0]); t[1] = (f16)(c1 * (float)qr[1]);
        t[2] = (f16)(c1 * (float)qr[2]); t[3] = (f16)(c1 * (float)qr[3]);
      }
      qf[u][m] = t;
    }

  f32x4 acc[2][4];
#pragma unroll
  for (int u = 0; u < 2; ++u)
#pragma unroll
    for (int m = 0; m < 4; ++m) acc[u][m] = (f32x4){0.f, 0.f, 0.f, 0.f};
  const f32x4 zero4 = {0.f, 0.f, 0.f, 0.f};

#pragma unroll 4
  for (int t = 0; t < 16; ++t) {
    f16x4 kf0 = *(const f16x4*)(kp0 + t * 256);
    f16x4 kf1 = *(const f16x4*)(kp1 + t * 256);
    f16x4 vf0 = *(const f16x4*)(vp0 + t * 256);
    f16x4 vf1 = *(const f16x4*)(vp1 + t * 256);
    f16x8 av0 = *(const f16x8*)(ap0 + t * 512);
    f16x8 av1 = *(const f16x8*)(ap1 + t * 512);
#pragma unroll
    for (int u = 0; u < 2; ++u) {
      f16x4 kfu = u ? kf1 : kf0;
      f16x4 vfu = u ? vf1 : vf0;
#pragma unroll
      for (int m = 0; m < 4; ++m) {
        f32x4 s = __builtin_amdgcn_mfma_f32_16x16x16f16(kfu, qf[u][m], zero4, 0, 0, 0);
        float a0 = (float)((m < 2 ? av0 : av1)[(m & 1) * 4 + 0]);
        float a1 = (float)((m < 2 ? av0 : av1)[(m & 1) * 4 + 1]);
        float a2 = (float)((m < 2 ? av0 : av1)[(m & 1) * 4 + 2]);
        float a3 = (float)((m < 2 ? av0 : av1)[(m & 1) * 4 + 3]);
        float e0 = __builtin_amdgcn_exp2f(s[0] + a0);
        float e1 = __builtin_amdgcn_exp2f(s[1] + a1);
        float e2 = __builtin_amdgcn_exp2f(s[2] + a2);
        float e3 = __builtin_amdgcn_exp2f(s[3] + a3);
        h16x2 p01 = __builtin_amdgcn_cvt_pkrtz(e0, e1);
        h16x2 p23 = __builtin_amdgcn_cvt_pkrtz(e2, e3);
        f16x4 pa;
        pa[0] = (f16)(float)p01[0]; pa[1] = (f16)(float)p01[1];
        pa[2] = (f16)(float)p23[0]; pa[3] = (f16)(float)p23[1];
        acc[u][m] = __builtin_amdgcn_mfma_f32_16x16x16f16(pa, vfu, acc[u][m], 0, 0, 0);
      }
    }
  }

  // merge 8 j-split partials; parallel epilogue: wave w reduces pair p=w.
  __shared__ f32x4 mlds[8][8][64];  // 64KB
#pragma unroll
  for (int u = 0; u < 2; ++u)
#pragma unroll
    for (int m = 0; m < 4; ++m) mlds[w][u * 4 + m][lane] = acc[u][m];
  __syncthreads();
  int p = w;
  f32x4 sum = mlds[0][p][lane];
#pragma unroll
  for (int s = 1; s < 8; ++s) {
    f32x4 o = mlds[s][p][lane];
    sum[0] += o[0]; sum[1] += o[1]; sum[2] += o[2]; sum[3] += o[3];
  }
  // sum(l,r) = out[q = qt0 + lh*4 + r][d = lq]; denominator at d=8
  int dsrc = (lane & 48) | 8;
  float d0 = __shfl(sum[0], dsrc);
  float d1 = __shfl(sum[1], dsrc);
  float d2 = __shfl(sum[2], dsrc);
  float d3 = __shfl(sum[3], dsrc);
  if (lq < 8) {
    int bh = bh0 + (p >> 2);
    int b = bh >> 2, h = bh & 3;
    int qt0 = (qtq * 4 + (p & 3)) * 16;
    size_t base = ((size_t)b * 2048 + qt0 + lh * 4) * 32 + h * 8 + lq;
    attn_ws[base]      = sum[0] / d0;
    attn_ws[base + 32] = sum[1] / d1;
    attn_ws[base + 64] = sum[2] / d2;
    attn_ws[base + 96] = sum[3] / d3;
  }
}

__global__ __launch_bounds__(256) void out_ln_kernel(
    const float* __restrict__ attn_ws, const float* __restrict__ x,
    const float* __restrict__ Wout, const float* __restrict__ bout,
    const float* __restrict__ gamma, const float* __restrict__ beta,
    float* __restrict__ out) {
  __shared__ float Ws[32 * 32];
  __shared__ float bs[32], gs[32], bts[32];
  int tid = threadIdx.x;
  for (int i = tid; i < 1024; i += 256) Ws[i] = Wout[i];
  if (tid < 32) { bs[tid] = bout[tid]; gs[tid] = gamma[tid]; bts[tid] = beta[tid]; }
  __syncthreads();
  int row = blockIdx.x * 8 + (tid >> 5);
  int d = tid & 31;
  const float* ar = attn_ws + (size_t)row * 32;
  float acc = bs[d];
#pragma unroll
  for (int k = 0; k < 32; ++k) acc += ar[k] * Ws[k * 32 + d];
  float res = acc + x[(size_t)row * 32 + d];
  float s1 = res, s2 = res * res;
#pragma unroll
  for (int off = 16; off >= 1; off >>= 1) {
    s1 += __shfl_xor(s1, off);
    s2 += __shfl_xor(s2, off);
  }
  float mu = s1 * 0.03125f;
  float var = s2 * 0.03125f - mu * mu;
  float r = rsqrtf(var + 1e-5f);
  out[(size_t)row * 32 + d] = (res - mu) * r * gs[d] + bts[d];
}

extern "C" void kernel_launch(void* const* d_in, const int* in_sizes, int n_in,
                              void* d_out, int out_size, void* d_ws, size_t ws_size,
                              hipStream_t stream) {
  const float* x     = (const float*)d_in[0];
  const float* adj   = (const float*)d_in[1];
  const float* gw    = (const float*)d_in[2];
  const float* Wqkv  = (const float*)d_in[3];
  const float* bqkv  = (const float*)d_in[4];
  const float* Wout  = (const float*)d_in[5];
  const float* bout  = (const float*)d_in[6];
  const float* gamma = (const float*)d_in[7];
  const float* beta  = (const float*)d_in[8];
  float* out = (float*)d_out;

  char* wsb = (char*)d_ws;
  f16* q16       = (f16*)wsb;                     // 1MB
  f16* kf_ws     = (f16*)(wsb + (1 << 20));       // 2MB
  f16* vf_ws     = (f16*)(wsb + (3 << 20));       // 2MB
  f16* adj16     = (f16*)(wsb + (5 << 20));       // 8MB
  float* attn_ws = (float*)(wsb + (13 << 20));    // 2MB

  qkv_kernel<<<1024, 256, 0, stream>>>(x, Wqkv, bqkv, q16, kf_ws, vf_ws);
  prep_kernel<<<2048, 256, 0, stream>>>(adj, gw, adj16, kf_ws, vf_ws);
  attn_kernel<<<512, 512, 0, stream>>>(q16, kf_ws, vf_ws, adj16, gw, attn_ws);
  out_ln_kernel<<<2048, 256, 0, stream>>>(attn_ws, x, Wout, bout, gamma, beta, out);
}